// Round 7
// baseline (212.429 us; speedup 1.0000x reference)
//
#include <hip/hip_runtime.h>
#include <math.h>

#define NB 4096   // batch
#define NS 64     // seq
#define NF 8      // feat
#define ND 64     // d_model
#define NL 4096   // NS*ND
#define NK 16     // top-k

typedef _Float16 half8 __attribute__((ext_vector_type(8)));
typedef float    f32x4 __attribute__((ext_vector_type(4)));

#define GLD16(src, dst) \
  __builtin_amdgcn_global_load_lds((const __attribute__((address_space(1))) void*)(src), \
                                   (__attribute__((address_space(3))) void*)(dst), 16, 0, 0)

#define WAITVM(N) asm volatile("s_waitcnt vmcnt(" #N ")" ::: "memory")

// ---------------- block reduce helper ----------------
__device__ __forceinline__ float blk_reduce(float v, float* red) {
    #pragma unroll
    for (int o = 32; o > 0; o >>= 1) v += __shfl_down(v, o, 64);
    const int t = threadIdx.x;
    __syncthreads();
    if ((t & 63) == 0) red[t >> 6] = v;
    __syncthreads();
    float r = 0.f;
    if (t == 0) r = red[0] + red[1] + red[2] + red[3];
    return r;
}

// ---- fused: x_enc = x@Wemb+b (fp16 store) ; proj = x_enc@Wp+bp ; term1 ----
__global__ __launch_bounds__(256) void embed_proj_kernel(
    const float* __restrict__ x, const float* __restrict__ Wemb,
    const float* __restrict__ bemb, const float* __restrict__ Wp,
    const float* __restrict__ bp,
    _Float16* __restrict__ Af, float* __restrict__ proj, double* __restrict__ acc)
{
    __shared__ float sW[NF * ND];      // [f][d]
    __shared__ float sbe[ND];
    __shared__ float sx[NS * NF];
    __shared__ float sWp[ND * NF];     // [d][f]
    __shared__ float sbp[NF];
    __shared__ float senc[NS * 65];    // stride-65 pad
    __shared__ float red[4];
    const int t = threadIdx.x, b = blockIdx.x;
    sW[t] = Wemb[t]; sW[t + 256] = Wemb[t + 256];
    sWp[t] = Wp[t];  sWp[t + 256] = Wp[t + 256];
    if (t < ND) sbe[t] = bemb[t];
    if (t < NF) sbp[t] = bp[t];
    sx[t] = x[(size_t)b * 512 + t];
    sx[t + 256] = x[(size_t)b * 512 + 256 + t];
    __syncthreads();
    const size_t rb = (size_t)b * NL;
    #pragma unroll
    for (int i = 0; i < 16; ++i) {
        const int idx = t + i * 256;
        const int s = idx >> 6, d = idx & 63;
        float a = sbe[d];
        #pragma unroll
        for (int f = 0; f < NF; ++f) a += sx[s * NF + f] * sW[f * ND + d];
        senc[s * 65 + d] = a;
        Af[rb + idx] = (_Float16)a;
    }
    __syncthreads();
    float s1 = 0.f;
    #pragma unroll
    for (int i = 0; i < 2; ++i) {
        const int e = t + i * 256;
        const int s = e >> 3, f = e & 7;
        float a = sbp[f];
        #pragma unroll
        for (int d = 0; d < ND; ++d) a += senc[s * 65 + d] * sWp[d * NF + f];
        proj[(size_t)b * 512 + e] = a;
        const float df = a - sx[e];
        s1 += df * df;
    }
    const float tot = blk_reduce(s1, red);
    if (t == 0) atomicAdd(&acc[(size_t)(blockIdx.x & 31) * 8], (double)tot);
}

// ---- attn = X@X^T fp16 MFMA, lower-tri, 3-buf depth-2 pipeline (48 KB -> 3 blocks/CU) ----
__global__ __launch_bounds__(256) void attn_gemm_kernel(
    const _Float16* __restrict__ Af, float* __restrict__ C)
{
    // 3 bufs x (A 4096 + B 4096 halves) = 48 KB; reused as [64][128] f32 for transpose
    __shared__ __align__(16) char smem_raw[49152];
    _Float16* smem = (_Float16*)smem_raw;

    const int t = threadIdx.x;
    const int lane = t & 63, wid = t >> 6;
    const int wr = wid >> 1, wc = wid & 1;     // 2x2 waves, each 64x64 out

    // XCD-chunked swizzle: 528 = 8 x 66
    const int bid0 = blockIdx.x;
    const int bid = (bid0 & 7) * 66 + (bid0 >> 3);

    // triangular block decode: bid -> (it, jt), jt <= it
    int it = (int)((sqrtf(8.0f * (float)bid + 1.0f) - 1.0f) * 0.5f);
    while ((it + 1) * (it + 2) / 2 <= bid) ++it;
    while (it * (it + 1) / 2 > bid) --it;
    const int jt = bid - it * (it + 1) / 2;
    const int i0 = it * 128, j0 = jt * 128;

    f32x4 acc[4][4];
    #pragma unroll
    for (int m = 0; m < 4; ++m)
        #pragma unroll
        for (int n = 0; n < 4; ++n) acc[m][n] = (f32x4){0.f, 0.f, 0.f, 0.f};

    const int lrow = lane & 15, g = lane >> 4;
    const int ksw = (g ^ ((lrow >> 1) & 3)) * 8;   // read-side chunk swizzle

    // hoisted per-thread staging addresses (source-side swizzle folded in)
    const int c0 = t, c1 = t + 256;
    const int r0 = c0 >> 2, r1 = c1 >> 2;
    const int cs0 = ((c0 & 3) ^ ((r0 >> 1) & 3)) * 8;
    const int cs1 = ((c1 & 3) ^ ((r1 >> 1) & 3)) * 8;
    const _Float16* pa0 = Af + (size_t)(i0 + r0) * NL + cs0;
    const _Float16* pa1 = Af + (size_t)(i0 + r1) * NL + cs1;
    const _Float16* pb0 = Af + (size_t)(j0 + r0) * NL + cs0;
    const _Float16* pb1 = Af + (size_t)(j0 + r1) * NL + cs1;
    _Float16* d0 = smem + c0 * 8;      // buf-0 LDS slots for this thread
    _Float16* d1 = smem + c1 * 8;

    // BUF and KH are compile-time literals at every call site
#define STG(BUF, KH) { \
    GLD16(pa0 + (KH), d0 + (BUF) * 8192); \
    GLD16(pa1 + (KH), d1 + (BUF) * 8192); \
    GLD16(pb0 + (KH), d0 + (BUF) * 8192 + 4096); \
    GLD16(pb1 + (KH), d1 + (BUF) * 8192 + 4096); }

    const int roA = wr * 2048 + lrow * 32 + ksw;
    const int roB = wc * 2048 + lrow * 32 + ksw;

#define COMPUTE(BUF) { \
    const _Float16* sA = smem + (BUF) * 8192; \
    const _Float16* sB = sA + 4096; \
    half8 fa[4], fb[4]; \
    _Pragma("unroll") \
    for (int m = 0; m < 4; ++m) { \
        fa[m] = *(const half8*)&sA[roA + m * 512]; \
        fb[m] = *(const half8*)&sB[roB + m * 512]; \
    } \
    __builtin_amdgcn_s_setprio(1); \
    _Pragma("unroll") \
    for (int m = 0; m < 4; ++m) \
        _Pragma("unroll") \
        for (int n = 0; n < 4; ++n) \
            acc[m][n] = __builtin_amdgcn_mfma_f32_16x16x32_f16(fa[m], fb[n], acc[m][n], 0, 0, 0); \
    __builtin_amdgcn_s_setprio(0); }

    // prologue: stages 0,1 (K-offsets 0,32 halves)
    STG(0, 0); STG(1, 32);
    pa0 += 64; pa1 += 64; pb0 += 64; pb1 += 64;   // -> stage-2 base

    // steady state: steps 0..125 in 42 unrolled iters; step s stages s+2, computes buf s%3
    #pragma unroll 1
    for (int io = 0; io < 42; ++io) {
        WAITVM(4); __builtin_amdgcn_s_barrier(); STG(2, 0);  COMPUTE(0);
        WAITVM(4); __builtin_amdgcn_s_barrier(); STG(0, 32); COMPUTE(1);
        WAITVM(4); __builtin_amdgcn_s_barrier(); STG(1, 64); COMPUTE(2);
        pa0 += 96; pa1 += 96; pb0 += 96; pb1 += 96;
    }
    // tail: steps 126 (buf 0), 127 (buf 1)
    WAITVM(4); __builtin_amdgcn_s_barrier(); COMPUTE(0);
    WAITVM(0); __builtin_amdgcn_s_barrier(); COMPUTE(1);
#undef STG
#undef COMPUTE

    // direct store (i-major), quarter-wave 64B segments
    const int diag = (it == jt);
    #pragma unroll
    for (int m = 0; m < 4; ++m)
        #pragma unroll
        for (int n = 0; n < 4; ++n)
            #pragma unroll
            for (int r = 0; r < 4; ++r) {
                const int i = i0 + wr * 64 + m * 16 + g * 4 + r;
                const int j = j0 + wc * 64 + n * 16 + lrow;
                C[(size_t)i * NB + j] = acc[m][n][r];
            }

    // mirror store via LDS transpose, two 64-row passes (fits 48 KB, coalesced)
    if (!diag) {
        float* fsm = (float*)smem_raw;     // [64][128] w/ XOR swizzle
        #pragma unroll
        for (int p = 0; p < 2; ++p) {
            __syncthreads();
            if (wc == p) {
                #pragma unroll
                for (int m = 0; m < 4; ++m)
                    #pragma unroll
                    for (int n = 0; n < 4; ++n) {
                        const int jl = n * 16 + lrow;          // 0..63 within pass
                        const int ilocb = wr * 64 + m * 16 + g * 4;
                        *(f32x4*)&fsm[jl * 128 + (ilocb ^ ((jl & 7) << 2))] = acc[m][n];
                    }
            }
            __syncthreads();
            #pragma unroll
            for (int rep = 0; rep < 8; ++rep) {
                const int idx = rep * 256 + t;
                const int jl = idx >> 5, ic4 = (idx & 31) * 4;
                const f32x4 v = *(const f32x4*)&fsm[jl * 128 + (ic4 ^ ((jl & 7) << 2))];
                *(f32x4*)&C[(size_t)(j0 + p * 64 + jl) * NB + i0 + ic4] = v;
            }
        }
    }
}

// ---------------- fused top-k + gathered diffs: one wave per row ----------------
__global__ __launch_bounds__(256) void topk_diffs_kernel(
    const float* __restrict__ attn, const float* __restrict__ proj, double* __restrict__ acc)
{
    __shared__ float rows[4][NB];   // 64 KB
    __shared__ int sidx[4][NK];
    const int t = threadIdx.x, lane = t & 63, w = t >> 6;
    const int b = blockIdx.x * 4 + w;
    float* srow = rows[w];
    const float4* src = (const float4*)(attn + (size_t)b * NB);
    #pragma unroll
    for (int j = 0; j < 16; ++j) {
        const int c4 = j * 64 + lane;
        *(float4*)&srow[c4 * 4] = src[c4];
    }
    if (lane == (b & 63)) srow[b] = -INFINITY;   // mask self (owner lane)

    // per-lane chunk caches: lane owns e with e%64==lane; 4 chunks of 16
    float cv[4]; int ci[4];
    #pragma unroll
    for (int q = 0; q < 4; ++q) {
        float bv = -INFINITY; int bi = 0;
        #pragma unroll
        for (int j = 0; j < 16; ++j) {
            const int e = (q * 16 + j) * 64 + lane;
            const float v = srow[e];
            if (v > bv) { bv = v; bi = e; }
        }
        cv[q] = bv; ci[q] = bi;
    }

    for (int k = 0; k < NK; ++k) {
        float bv = cv[0]; int bi = ci[0];
        #pragma unroll
        for (int q = 1; q < 4; ++q)
            if (cv[q] > bv || (cv[q] == bv && ci[q] < bi)) { bv = cv[q]; bi = ci[q]; }
        float v = bv; int idx = bi;
        #pragma unroll
        for (int o = 32; o > 0; o >>= 1) {
            const float v2 = __shfl_xor(v, o, 64);
            const int  i2 = __shfl_xor(idx, o, 64);
            if (v2 > v || (v2 == v && i2 < idx)) { v = v2; idx = i2; }
        }
        if (lane == 0) sidx[w][k] = idx;
        if ((idx & 63) == lane) {                 // owner invalidates + rescans chunk
            srow[idx] = -INFINITY;
            const int q = idx >> 10;
            float nbv = -INFINITY; int nbi = 0;
            #pragma unroll
            for (int j = 0; j < 16; ++j) {
                const int e = (q * 16 + j) * 64 + lane;
                const float v3 = srow[e];
                if (v3 > nbv) { nbv = v3; nbi = e; }
            }
            cv[q] = nbv; ci[q] = nbi;
        }
    }

    // diffs: stream 16 gathered proj rows; lane holds 8 consecutive floats
    float s1 = 0.f, s2 = 0.f;
    float prev[8];
    for (int k = 0; k < NK; ++k) {
        const float4* p = (const float4*)(proj + (size_t)sidx[w][k] * 512 + lane * 8);
        const float4 a0 = p[0], a1 = p[1];
        float cur[8] = {a0.x, a0.y, a0.z, a0.w, a1.x, a1.y, a1.z, a1.w};
        if (k) {
            #pragma unroll
            for (int j = 0; j < 8; ++j) { const float d = cur[j] - prev[j]; s1 += d * d; }
        }
        #pragma unroll
        for (int j = 0; j < 8; ++j) {
            const float nb = __shfl_down(cur[j], 1, 64);
            if (lane < 63) { const float d = nb - cur[j]; s2 += d * d; }
        }
        #pragma unroll
        for (int j = 0; j < 8; ++j) prev[j] = cur[j];
    }
    #pragma unroll
    for (int o = 32; o > 0; o >>= 1) { s1 += __shfl_down(s1, o, 64); s2 += __shfl_down(s2, o, 64); }
    if (lane == 0) {
        const size_t slot = (size_t)(blockIdx.x & 31) * 8;
        atomicAdd(&acc[(size_t)32 * 8 + slot], (double)s1);
        atomicAdd(&acc[(size_t)64 * 8 + slot], (double)s2);
    }
}

// ---------------- finalize loss ----------------
__global__ void finalize_kernel(const double* __restrict__ acc, float* __restrict__ out) {
    if (threadIdx.x == 0) {
        double s0 = 0.0, s1 = 0.0, s2 = 0.0;
        #pragma unroll
        for (int i = 0; i < 32; ++i) {
            s0 += acc[(size_t)i * 8];
            s1 += acc[(size_t)(32 + i) * 8];
            s2 += acc[(size_t)(64 + i) * 8];
        }
        out[0] = (float)(s0 / 2097152.0 + s1 / 31457280.0 + s2 / 33030144.0);
    }
}

extern "C" void kernel_launch(void* const* d_in, const int* in_sizes, int n_in,
                              void* d_out, int out_size, void* d_ws, size_t ws_size,
                              hipStream_t stream) {
    const float* x    = (const float*)d_in[0];
    const float* Wemb = (const float*)d_in[1];
    const float* bemb = (const float*)d_in[2];
    const float* Wp   = (const float*)d_in[3];
    const float* bp   = (const float*)d_in[4];
    float* out  = (float*)d_out;
    float* proj = out + 1;                       // x_rec_proj, B*S*F floats

    char* ws = (char*)d_ws;
    _Float16* Af   = (_Float16*)ws;                            // 32 MB
    float*  attn   = (float*)(ws + ((size_t)32 << 20));        // 64 MB
    double* acc    = (double*)(ws + ((size_t)96 << 20));       // 96 slots x 64B stride

    hipMemsetAsync(acc, 0, 96 * 8 * sizeof(double), stream);
    embed_proj_kernel<<<NB, 256, 0, stream>>>(x, Wemb, bemb, Wp, bp, Af, proj, acc);
    attn_gemm_kernel<<<(32 * 33) / 2, 256, 0, stream>>>(Af, attn);
    topk_diffs_kernel<<<NB / 4, 256, 0, stream>>>(attn, proj, acc);
    finalize_kernel<<<1, 64, 0, stream>>>(acc, out);
}

// Round 8
// 106.211 us; speedup vs baseline: 2.0001x; 2.0001x over previous
//
#include <hip/hip_runtime.h>
#include <math.h>

#define NB 4096   // batch
#define NS 64     // seq
#define NF 8      // feat
#define ND 64     // d_model
#define KL 512    // GEMM K = NS*NF (rank-8 trick)
#define NK 16     // top-k

typedef _Float16 half8 __attribute__((ext_vector_type(8)));
typedef float    f32x4 __attribute__((ext_vector_type(4)));

#define GLD16(src, dst) \
  __builtin_amdgcn_global_load_lds((const __attribute__((address_space(1))) void*)(src), \
                                   (__attribute__((address_space(3))) void*)(dst), 16, 0, 0)

#define WAITVM(N) asm volatile("s_waitcnt vmcnt(" #N ")" ::: "memory")

// ---------------- block reduce helper ----------------
__device__ __forceinline__ float blk_reduce(float v, float* red) {
    #pragma unroll
    for (int o = 32; o > 0; o >>= 1) v += __shfl_down(v, o, 64);
    const int t = threadIdx.x;
    __syncthreads();
    if ((t & 63) == 0) red[t >> 6] = v;
    __syncthreads();
    float r = 0.f;
    if (t == 0) r = red[0] + red[1] + red[2] + red[3];
    return r;
}

// ---- consts: G = We@We^T [8x8], M = We@Wp [8x8], u = We@be [8], c8 = be@Wp + bp [8] ----
__global__ __launch_bounds__(64) void consts_kernel(
    const float* __restrict__ Wemb, const float* __restrict__ bemb,
    const float* __restrict__ Wp, const float* __restrict__ bp, float* __restrict__ cst)
{
    __shared__ float sWe[NF * ND];   // [f][d]
    __shared__ float sWp[ND * NF];   // [d][f]
    __shared__ float sbe[ND];
    __shared__ float sbp[NF];
    const int t = threadIdx.x;
    #pragma unroll
    for (int i = 0; i < 8; ++i) { sWe[t + i * 64] = Wemb[t + i * 64]; sWp[t + i * 64] = Wp[t + i * 64]; }
    sbe[t] = bemb[t];
    if (t < NF) sbp[t] = bp[t];
    __syncthreads();
    const int f = t >> 3, f2 = t & 7;
    float g = 0.f, m = 0.f;
    #pragma unroll
    for (int d = 0; d < ND; ++d) {
        g += sWe[f * ND + d] * sWe[f2 * ND + d];
        m += sWe[f * ND + d] * sWp[d * NF + f2];
    }
    cst[t] = g;          // G[f][f2]
    cst[64 + t] = m;     // M[f][f2]
    if (t < NF) {
        float uu = 0.f, cc = 0.f;
        #pragma unroll
        for (int d = 0; d < ND; ++d) {
            uu += sWe[t * ND + d] * sbe[d];
            cc += sbe[d] * sWp[d * NF + t];
        }
        cst[128 + t] = uu;            // u[f]
        cst[136 + t] = cc + sbp[t];   // c8[f]
    }
}

// ---- prep: X16=fp16(x), Y16=fp16(x@G), proj=x@M+c8, r[b]=sum_s x.u, term1 ----
// one wave per batch row (lane = s), 4 rows per block
__global__ __launch_bounds__(256) void prep_kernel(
    const float* __restrict__ x, const float* __restrict__ cst,
    _Float16* __restrict__ X16, _Float16* __restrict__ Y16,
    float* __restrict__ proj, float* __restrict__ r, double* __restrict__ acc)
{
    __shared__ float sG[64], sM[64], su[8], sc[8];
    __shared__ float red[4];
    const int t = threadIdx.x, lane = t & 63, w = t >> 6;
    if (t < 64) sG[t] = cst[t];
    else if (t < 128) sM[t - 64] = cst[t];
    else if (t < 136) su[t - 128] = cst[t];
    else if (t < 144) sc[t - 136] = cst[t];
    __syncthreads();
    const int b = blockIdx.x * 4 + w;
    const size_t base = (size_t)b * KL + lane * 8;
    const f32x4 x0 = *(const f32x4*)&x[base];
    const f32x4 x1 = *(const f32x4*)&x[base + 4];
    float xv[8] = {x0[0], x0[1], x0[2], x0[3], x1[0], x1[1], x1[2], x1[3]};
    float yv[8], pv[8];
    #pragma unroll
    for (int f2 = 0; f2 < 8; ++f2) { yv[f2] = 0.f; pv[f2] = sc[f2]; }
    #pragma unroll
    for (int f = 0; f < 8; ++f)
        #pragma unroll
        for (int f2 = 0; f2 < 8; ++f2) {
            yv[f2] += xv[f] * sG[f * 8 + f2];
            pv[f2] += xv[f] * sM[f * 8 + f2];
        }
    half8 hx, hy;
    #pragma unroll
    for (int j = 0; j < 8; ++j) { hx[j] = (_Float16)xv[j]; hy[j] = (_Float16)yv[j]; }
    *(half8*)&X16[base] = hx;
    *(half8*)&Y16[base] = hy;
    *(f32x4*)&proj[base] = (f32x4){pv[0], pv[1], pv[2], pv[3]};
    *(f32x4*)&proj[base + 4] = (f32x4){pv[4], pv[5], pv[6], pv[7]};
    // r[b] = sum_s x[b,s].u  (wave reduce, lane = s)
    float rv = 0.f;
    #pragma unroll
    for (int f = 0; f < 8; ++f) rv += xv[f] * su[f];
    #pragma unroll
    for (int o = 32; o > 0; o >>= 1) rv += __shfl_down(rv, o, 64);
    if (lane == 0) r[b] = rv;
    // term1
    float s1 = 0.f;
    #pragma unroll
    for (int j = 0; j < 8; ++j) { const float d = pv[j] - xv[j]; s1 += d * d; }
    const float tot = blk_reduce(s1, red);
    if (t == 0) atomicAdd(&acc[(size_t)(blockIdx.x & 31) * 8], (double)tot);
}

// ---- dot = X @ Y^T (K=512) fp16 MFMA, lower-tri, 3-buf depth-2 pipeline ----
__global__ __launch_bounds__(256) void attn_gemm_kernel(
    const _Float16* __restrict__ Xf, const _Float16* __restrict__ Yf, float* __restrict__ C)
{
    // 3 bufs x (A 4096 + B 4096 halves) = 48 KB; reused as [64][128] f32 for transpose
    __shared__ __align__(16) char smem_raw[49152];
    _Float16* smem = (_Float16*)smem_raw;

    const int t = threadIdx.x;
    const int lane = t & 63, wid = t >> 6;
    const int wr = wid >> 1, wc = wid & 1;     // 2x2 waves, each 64x64 out

    // XCD-chunked swizzle: 528 = 8 x 66
    const int bid0 = blockIdx.x;
    const int bid = (bid0 & 7) * 66 + (bid0 >> 3);

    // triangular block decode: bid -> (it, jt), jt <= it
    int it = (int)((sqrtf(8.0f * (float)bid + 1.0f) - 1.0f) * 0.5f);
    while ((it + 1) * (it + 2) / 2 <= bid) ++it;
    while (it * (it + 1) / 2 > bid) --it;
    const int jt = bid - it * (it + 1) / 2;
    const int i0 = it * 128, j0 = jt * 128;

    f32x4 acc[4][4];
    #pragma unroll
    for (int m = 0; m < 4; ++m)
        #pragma unroll
        for (int n = 0; n < 4; ++n) acc[m][n] = (f32x4){0.f, 0.f, 0.f, 0.f};

    const int lrow = lane & 15, g = lane >> 4;
    const int ksw = (g ^ ((lrow >> 1) & 3)) * 8;   // read-side chunk swizzle

    // hoisted per-thread staging addresses (source-side swizzle folded in)
    const int c0 = t, c1 = t + 256;
    const int r0 = c0 >> 2, r1 = c1 >> 2;
    const int cs0 = ((c0 & 3) ^ ((r0 >> 1) & 3)) * 8;
    const int cs1 = ((c1 & 3) ^ ((r1 >> 1) & 3)) * 8;
    const _Float16* pa0 = Xf + (size_t)(i0 + r0) * KL + cs0;
    const _Float16* pa1 = Xf + (size_t)(i0 + r1) * KL + cs1;
    const _Float16* pb0 = Yf + (size_t)(j0 + r0) * KL + cs0;
    const _Float16* pb1 = Yf + (size_t)(j0 + r1) * KL + cs1;
    _Float16* d0 = smem + c0 * 8;
    _Float16* d1 = smem + c1 * 8;

#define STG(BUF, KH) { \
    GLD16(pa0 + (KH), d0 + (BUF) * 8192); \
    GLD16(pa1 + (KH), d1 + (BUF) * 8192); \
    GLD16(pb0 + (KH), d0 + (BUF) * 8192 + 4096); \
    GLD16(pb1 + (KH), d1 + (BUF) * 8192 + 4096); }

    const int roA = wr * 2048 + lrow * 32 + ksw;
    const int roB = wc * 2048 + lrow * 32 + ksw;

#define COMPUTE(BUF) { \
    const _Float16* sA = smem + (BUF) * 8192; \
    const _Float16* sB = sA + 4096; \
    half8 fa[4], fb[4]; \
    _Pragma("unroll") \
    for (int m = 0; m < 4; ++m) { \
        fa[m] = *(const half8*)&sA[roA + m * 512]; \
        fb[m] = *(const half8*)&sB[roB + m * 512]; \
    } \
    __builtin_amdgcn_s_setprio(1); \
    _Pragma("unroll") \
    for (int m = 0; m < 4; ++m) \
        _Pragma("unroll") \
        for (int n = 0; n < 4; ++n) \
            acc[m][n] = __builtin_amdgcn_mfma_f32_16x16x32_f16(fa[m], fb[n], acc[m][n], 0, 0, 0); \
    __builtin_amdgcn_s_setprio(0); }

    // 16 K-steps: prologue stages 0,1; steady stages s+2; tail computes
    STG(0, 0); STG(1, 32);
    pa0 += 64; pa1 += 64; pb0 += 64; pb1 += 64;
    #pragma unroll 1
    for (int io = 0; io < 4; ++io) {
        WAITVM(4); __builtin_amdgcn_s_barrier(); STG(2, 0);  COMPUTE(0);
        WAITVM(4); __builtin_amdgcn_s_barrier(); STG(0, 32); COMPUTE(1);
        WAITVM(4); __builtin_amdgcn_s_barrier(); STG(1, 64); COMPUTE(2);
        pa0 += 96; pa1 += 96; pb0 += 96; pb1 += 96;
    }
    WAITVM(4); __builtin_amdgcn_s_barrier(); STG(2, 0);  COMPUTE(0);   // stage 14
    WAITVM(4); __builtin_amdgcn_s_barrier(); STG(0, 32); COMPUTE(1);   // stage 15
    WAITVM(4); __builtin_amdgcn_s_barrier(); COMPUTE(2);
    WAITVM(0); __builtin_amdgcn_s_barrier(); COMPUTE(0);
#undef STG
#undef COMPUTE

    // direct store (i-major), quarter-wave 64B segments
    const int diag = (it == jt);
    #pragma unroll
    for (int m = 0; m < 4; ++m)
        #pragma unroll
        for (int n = 0; n < 4; ++n)
            #pragma unroll
            for (int rr = 0; rr < 4; ++rr) {
                const int i = i0 + wr * 64 + m * 16 + g * 4 + rr;
                const int j = j0 + wc * 64 + n * 16 + lrow;
                C[(size_t)i * NB + j] = acc[m][n][rr];
            }

    // mirror store via LDS transpose, two 64-row passes (fits 48 KB, coalesced)
    if (!diag) {
        float* fsm = (float*)smem_raw;     // [64][128] w/ XOR swizzle
        #pragma unroll
        for (int p = 0; p < 2; ++p) {
            __syncthreads();
            if (wc == p) {
                #pragma unroll
                for (int m = 0; m < 4; ++m)
                    #pragma unroll
                    for (int n = 0; n < 4; ++n) {
                        const int jl = n * 16 + lrow;
                        const int ilocb = wr * 64 + m * 16 + g * 4;
                        *(f32x4*)&fsm[jl * 128 + (ilocb ^ ((jl & 7) << 2))] = acc[m][n];
                    }
            }
            __syncthreads();
            #pragma unroll
            for (int rep = 0; rep < 8; ++rep) {
                const int idx = rep * 256 + t;
                const int jl = idx >> 5, ic4 = (idx & 31) * 4;
                const f32x4 v = *(const f32x4*)&fsm[jl * 128 + (ic4 ^ ((jl & 7) << 2))];
                *(f32x4*)&C[(size_t)(j0 + p * 64 + jl) * NB + i0 + ic4] = v;
            }
        }
    }
}

// ---------------- fused top-k + gathered diffs: one wave per row ----------------
__global__ __launch_bounds__(256) void topk_diffs_kernel(
    const float* __restrict__ attn, const float* __restrict__ radd,
    const float* __restrict__ proj, double* __restrict__ acc)
{
    __shared__ float rows[4][NB];   // 64 KB
    __shared__ int sidx[4][NK];
    const int t = threadIdx.x, lane = t & 63, w = t >> 6;
    const int b = blockIdx.x * 4 + w;
    float* srow = rows[w];
    const float4* src = (const float4*)(attn + (size_t)b * NB);
    const float4* rad4 = (const float4*)radd;
    #pragma unroll
    for (int j = 0; j < 16; ++j) {
        const int c4 = j * 64 + lane;
        const float4 a = src[c4], rr = rad4[c4];
        float4 v;
        v.x = a.x + rr.x; v.y = a.y + rr.y; v.z = a.z + rr.z; v.w = a.w + rr.w;
        *(float4*)&srow[c4 * 4] = v;
    }
    if (lane == (b & 63)) srow[b] = -INFINITY;   // mask self (owner lane)

    // per-lane chunk caches: lane owns e with e%64==lane; 4 chunks of 16
    float cv[4]; int ci[4];
    #pragma unroll
    for (int q = 0; q < 4; ++q) {
        float bv = -INFINITY; int bi = 0;
        #pragma unroll
        for (int j = 0; j < 16; ++j) {
            const int e = (q * 16 + j) * 64 + lane;
            const float v = srow[e];
            if (v > bv) { bv = v; bi = e; }
        }
        cv[q] = bv; ci[q] = bi;
    }

    for (int k = 0; k < NK; ++k) {
        float bv = cv[0]; int bi = ci[0];
        #pragma unroll
        for (int q = 1; q < 4; ++q)
            if (cv[q] > bv || (cv[q] == bv && ci[q] < bi)) { bv = cv[q]; bi = ci[q]; }
        float v = bv; int idx = bi;
        #pragma unroll
        for (int o = 32; o > 0; o >>= 1) {
            const float v2 = __shfl_xor(v, o, 64);
            const int  i2 = __shfl_xor(idx, o, 64);
            if (v2 > v || (v2 == v && i2 < idx)) { v = v2; idx = i2; }
        }
        if (lane == 0) sidx[w][k] = idx;
        if ((idx & 63) == lane) {                 // owner invalidates + rescans chunk
            srow[idx] = -INFINITY;
            const int q = idx >> 10;
            float nbv = -INFINITY; int nbi = 0;
            #pragma unroll
            for (int j = 0; j < 16; ++j) {
                const int e = (q * 16 + j) * 64 + lane;
                const float v3 = srow[e];
                if (v3 > nbv) { nbv = v3; nbi = e; }
            }
            cv[q] = nbv; ci[q] = nbi;
        }
    }

    // diffs: stream 16 gathered proj rows; lane holds 8 consecutive floats
    float s1 = 0.f, s2 = 0.f;
    float prev[8];
    for (int k = 0; k < NK; ++k) {
        const float4* p = (const float4*)(proj + (size_t)sidx[w][k] * 512 + lane * 8);
        const float4 a0 = p[0], a1 = p[1];
        float cur[8] = {a0.x, a0.y, a0.z, a0.w, a1.x, a1.y, a1.z, a1.w};
        if (k) {
            #pragma unroll
            for (int j = 0; j < 8; ++j) { const float d = cur[j] - prev[j]; s1 += d * d; }
        }
        #pragma unroll
        for (int j = 0; j < 8; ++j) {
            const float nb = __shfl_down(cur[j], 1, 64);
            if (lane < 63) { const float d = nb - cur[j]; s2 += d * d; }
        }
        #pragma unroll
        for (int j = 0; j < 8; ++j) prev[j] = cur[j];
    }
    #pragma unroll
    for (int o = 32; o > 0; o >>= 1) { s1 += __shfl_down(s1, o, 64); s2 += __shfl_down(s2, o, 64); }
    if (lane == 0) {
        const size_t slot = (size_t)(blockIdx.x & 31) * 8;
        atomicAdd(&acc[(size_t)32 * 8 + slot], (double)s1);
        atomicAdd(&acc[(size_t)64 * 8 + slot], (double)s2);
    }
}

// ---------------- finalize loss ----------------
__global__ void finalize_kernel(const double* __restrict__ acc, float* __restrict__ out) {
    if (threadIdx.x == 0) {
        double s0 = 0.0, s1 = 0.0, s2 = 0.0;
        #pragma unroll
        for (int i = 0; i < 32; ++i) {
            s0 += acc[(size_t)i * 8];
            s1 += acc[(size_t)(32 + i) * 8];
            s2 += acc[(size_t)(64 + i) * 8];
        }
        out[0] = (float)(s0 / 2097152.0 + s1 / 31457280.0 + s2 / 33030144.0);
    }
}

extern "C" void kernel_launch(void* const* d_in, const int* in_sizes, int n_in,
                              void* d_out, int out_size, void* d_ws, size_t ws_size,
                              hipStream_t stream) {
    const float* x    = (const float*)d_in[0];
    const float* Wemb = (const float*)d_in[1];
    const float* bemb = (const float*)d_in[2];
    const float* Wp   = (const float*)d_in[3];
    const float* bp   = (const float*)d_in[4];
    float* out  = (float*)d_out;
    float* proj = out + 1;                       // x_rec_proj, B*S*F floats

    char* ws = (char*)d_ws;
    _Float16* X16 = (_Float16*)ws;                               // 4 MB
    _Float16* Y16 = (_Float16*)(ws + ((size_t)4 << 20));         // 4 MB
    float*  attn  = (float*)(ws + ((size_t)8 << 20));            // 64 MB
    float*  cst   = (float*)(ws + ((size_t)72 << 20));           // 256 floats
    float*  rvec  = (float*)(ws + ((size_t)72 << 20) + 4096);    // 16 KB
    double* acc   = (double*)(ws + ((size_t)72 << 20) + 65536);  // 96 slots x 64B

    hipMemsetAsync(acc, 0, 96 * 8 * sizeof(double), stream);
    consts_kernel<<<1, 64, 0, stream>>>(Wemb, bemb, Wp, bp, cst);
    prep_kernel<<<NB / 4, 256, 0, stream>>>(x, cst, X16, Y16, proj, rvec, acc);
    attn_gemm_kernel<<<(32 * 33) / 2, 256, 0, stream>>>(X16, Y16, attn);
    topk_diffs_kernel<<<NB / 4, 256, 0, stream>>>(attn, rvec, proj, acc);
    finalize_kernel<<<1, 64, 0, stream>>>(acc, out);
}